// Round 1
// baseline (2161.752 us; speedup 1.0000x reference)
//
#include <hip/hip_runtime.h>

#define NOBS 2048
#define NX   128
#define NY   64
#define BS   8            // scenarios per solver block
#define NT   1024         // solver block threads (16 waves)
#define NWAVE (NT / 64)
#define NITER 64

// ---- DPP wave reductions (VALU pipe, keeps LDS pipe free) ----
template <int CTRL>
__device__ __forceinline__ float dpp_f(float x) {
    return __int_as_float(__builtin_amdgcn_update_dpp(
        0, __float_as_int(x), CTRL, 0xf, 0xf, true));  // bound_ctrl: invalid lanes read 0
}
// After these, lane 63 holds the full-wave result.
__device__ __forceinline__ float wave_sum64(float v) {
    v += dpp_f<0x111>(v);   // row_shr:1
    v += dpp_f<0x112>(v);   // row_shr:2
    v += dpp_f<0x114>(v);   // row_shr:4
    v += dpp_f<0x118>(v);   // row_shr:8  -> lane 16r+15 = row sum
    v += dpp_f<0x142>(v);   // row_bcast15
    v += dpp_f<0x143>(v);   // row_bcast31 -> lane 63 = total
    return v;
}
__device__ __forceinline__ float wave_max64_nonneg(float v) {  // requires v >= 0 (0-fill safe)
    v = fmaxf(v, dpp_f<0x111>(v));
    v = fmaxf(v, dpp_f<0x112>(v));
    v = fmaxf(v, dpp_f<0x114>(v));
    v = fmaxf(v, dpp_f<0x118>(v));
    v = fmaxf(v, dpp_f<0x142>(v));
    v = fmaxf(v, dpp_f<0x143>(v));
    return v;
}

// ---- Kernel 1: Y_hat = X@W^T + b ; ep = Y - Y_hat ; epsum = sum(ep) ----
__global__ __launch_bounds__(256) void prep_kernel(
    const float* __restrict__ X, const float* __restrict__ Y,
    const float* __restrict__ W, const float* __restrict__ b,
    float* __restrict__ yhat_out, float* __restrict__ ep, float* __restrict__ epsum)
{
    __shared__ float Xs[4][NX];
    const int t = threadIdx.x;
    const int row0 = blockIdx.x * 4;
    for (int f = t; f < 4 * NX; f += 256)
        Xs[f >> 7][f & 127] = X[(row0 + (f >> 7)) * NX + (f & 127)];
    __syncthreads();

    const int k = t & 63;
    const int r = t >> 6;
    const float4* W4 = reinterpret_cast<const float4*>(W + k * NX);
    const float4* X4 = reinterpret_cast<const float4*>(&Xs[r][0]);
    float acc = 0.f;
    #pragma unroll
    for (int x = 0; x < NX / 4; ++x) {
        float4 wv = W4[x];
        float4 xv = X4[x];
        acc += wv.x * xv.x + wv.y * xv.y + wv.z * xv.z + wv.w * xv.w;
    }
    const float yh = acc + b[k];
    const int i = row0 + r;
    yhat_out[i * NY + k] = yh;
    const float e = Y[i * NY + k] - yh;
    ep[i * NY + k] = e;

    float se = wave_sum64(e);
    if ((t & 63) == 63) atomicAdd(epsum, se);
}

// ---- Kernel 2: batched projected-subgradient DRO solve ----
__global__ __launch_bounds__(NT, 4) void solve_kernel(
    const float* __restrict__ ep, const float* __restrict__ yhat,
    const float* __restrict__ epsum, const float* __restrict__ rho_p,
    float* __restrict__ zout)
{
    __shared__ float Zs[BS][NY];          // 2 KB  current z per scenario
    __shared__ float Yh[BS][NY];          // 2 KB
    __shared__ float V[NOBS][BS];         // 64 KB weighted residual v = omega .* s
    __shared__ float Rpart[NWAVE][NY][BS];// 32 KB per-wave partial r
    __shared__ float Rr[NY][BS];          // 2 KB  r = ep^T v
    __shared__ float redBuf[NWAVE][32];   // 2 KB
    __shared__ float scal[32];
    __shared__ float umaxS[BS], cS[BS], lamS[BS], gcS[BS], glamS[BS], wAS[BS];

    const int t = threadIdx.x;
    const int lane = t & 63;
    const int wv = t >> 6;
    const int sc0 = blockIdx.x * BS;
    const float rho = rho_p[0];

    if (t < BS * NY) {
        const int j = t >> 6, k = t & 63;
        Yh[j][k] = yhat[(sc0 + j) * NY + k];
        Zs[j][k] = 1.0f / 64.0f;
    }
    if (t < BS) {
        cS[t] = epsum[0] * (1.0f / 131072.0f);  // mean(ep) == mean(ep @ z0)
        lamS[t] = 1.0f;
    }
    __syncthreads();

    const int i0 = t;          // each thread owns obs rows t and t+1024
    const int i1 = t + NT;
    const float4* ep4 = reinterpret_cast<const float4*>(ep);

    for (int it = 0; it < NITER; ++it) {
        const float lr = 0.05f / sqrtf((float)it + 1.0f);

        // ---- Phase A: s = ep.z - c for 2 rows x 8 scenarios ----
        float s0[BS], s1[BS];
        #pragma unroll
        for (int j = 0; j < BS; ++j) { s0[j] = 0.f; s1[j] = 0.f; }
        #pragma unroll 4
        for (int k4 = 0; k4 < NY / 4; ++k4) {
            const float4 ea = ep4[i0 * (NY / 4) + k4];
            const float4 eb = ep4[i1 * (NY / 4) + k4];
            #pragma unroll
            for (int j = 0; j < BS; ++j) {
                const float4 zv = *reinterpret_cast<const float4*>(&Zs[j][k4 * 4]);
                s0[j] += ea.x * zv.x + ea.y * zv.y + ea.z * zv.z + ea.w * zv.w;
                s1[j] += eb.x * zv.x + eb.y * zv.y + eb.z * zv.z + eb.w * zv.w;
            }
        }
        float lamR[BS];
        #pragma unroll
        for (int j = 0; j < BS; ++j) {
            const float cj = cS[j];
            lamR[j] = lamS[j];
            s0[j] -= cj; s1[j] -= cj;
        }

        // ---- Phase B1: umax per scenario ----
        #pragma unroll
        for (int j = 0; j < BS; ++j) {
            float pm = fmaxf(s0[j] * s0[j], s1[j] * s1[j]);
            pm = wave_max64_nonneg(pm);
            if (lane == 63) redBuf[wv][j] = pm;
        }
        __syncthreads();
        if (t < BS) {
            float m = redBuf[0][t];
            #pragma unroll
            for (int w = 1; w < NWAVE; ++w) m = fmaxf(m, redBuf[w][t]);
            umaxS[t] = m;
        }
        __syncthreads();

        // ---- Phase B2: sums of a, eq, a*s, eq*s (JAX balanced-tie semantics) ----
        #pragma unroll
        for (int j = 0; j < BS; ++j) {
            const float um = umaxS[j], lm = lamR[j];
            float pa = 0.f, pe = 0.f, pas = 0.f, pes = 0.f;
            {
                const float s = s0[j], u = s * s;
                const float x = (u - um) + lm;
                const float a = (x > -lm) ? 1.0f : ((x == -lm) ? 0.5f : 0.0f);
                const float e = (u == um) ? 1.0f : 0.0f;
                pa += a; pe += e; pas += a * s; pes += e * s;
            }
            {
                const float s = s1[j], u = s * s;
                const float x = (u - um) + lm;
                const float a = (x > -lm) ? 1.0f : ((x == -lm) ? 0.5f : 0.0f);
                const float e = (u == um) ? 1.0f : 0.0f;
                pa += a; pe += e; pas += a * s; pes += e * s;
            }
            pa = wave_sum64(pa); pe = wave_sum64(pe);
            pas = wave_sum64(pas); pes = wave_sum64(pes);
            if (lane == 63) {
                redBuf[wv][j] = pa;       redBuf[wv][8 + j] = pe;
                redBuf[wv][16 + j] = pas; redBuf[wv][24 + j] = pes;
            }
        }
        __syncthreads();
        if (t < 32) {
            float ssum = 0.f;
            #pragma unroll
            for (int w = 0; w < NWAVE; ++w) ssum += redBuf[w][t];
            scal[t] = ssum;
        }
        __syncthreads();
        if (t < BS) {
            const int j = t;
            const float sumA = scal[j], sumEq = scal[8 + j];
            const float sumAS = scal[16 + j], sumEqS = scal[24 + j];
            const float abar = sumA * (1.0f / (float)NOBS);
            const float wA = (1.0f - abar) / sumEq;   // argmax weight / tie count
            wAS[j] = wA;
            gcS[j] = -2.0f * (sumAS * (1.0f / (float)NOBS) + wA * sumEqS);
            glamS[j] = (rho - 2.0f) + 2.0f * abar;
        }
        __syncthreads();

        // ---- Phase B4: v = (a/n + eq*(1-abar)/count) * s into LDS ----
        {
            float v0[BS], v1[BS];
            #pragma unroll
            for (int j = 0; j < BS; ++j) {
                const float um = umaxS[j], lm = lamR[j], wA = wAS[j];
                {
                    const float s = s0[j], u = s * s;
                    const float x = (u - um) + lm;
                    const float a = (x > -lm) ? 1.0f : ((x == -lm) ? 0.5f : 0.0f);
                    const float e = (u == um) ? 1.0f : 0.0f;
                    v0[j] = (a * (1.0f / (float)NOBS) + e * wA) * s;
                }
                {
                    const float s = s1[j], u = s * s;
                    const float x = (u - um) + lm;
                    const float a = (x > -lm) ? 1.0f : ((x == -lm) ? 0.5f : 0.0f);
                    const float e = (u == um) ? 1.0f : 0.0f;
                    v1[j] = (a * (1.0f / (float)NOBS) + e * wA) * s;
                }
            }
            *reinterpret_cast<float4*>(&V[i0][0]) = make_float4(v0[0], v0[1], v0[2], v0[3]);
            *reinterpret_cast<float4*>(&V[i0][4]) = make_float4(v0[4], v0[5], v0[6], v0[7]);
            *reinterpret_cast<float4*>(&V[i1][0]) = make_float4(v1[0], v1[1], v1[2], v1[3]);
            *reinterpret_cast<float4*>(&V[i1][4]) = make_float4(v1[4], v1[5], v1[6], v1[7]);
        }
        __syncthreads();

        // ---- Phase C: r = ep^T v (wave g covers 128 obs; lane = column k) ----
        {
            float rp[BS];
            #pragma unroll
            for (int j = 0; j < BS; ++j) rp[j] = 0.f;
            const int ibeg = wv * (NOBS / NWAVE);
            #pragma unroll 4
            for (int ii = 0; ii < NOBS / NWAVE; ++ii) {
                const int i = ibeg + ii;
                const float e = ep[i * NY + lane];                       // coalesced
                const float4 va = *reinterpret_cast<const float4*>(&V[i][0]);  // broadcast
                const float4 vb = *reinterpret_cast<const float4*>(&V[i][4]);  // broadcast
                rp[0] += e * va.x; rp[1] += e * va.y; rp[2] += e * va.z; rp[3] += e * va.w;
                rp[4] += e * vb.x; rp[5] += e * vb.y; rp[6] += e * vb.z; rp[7] += e * vb.w;
            }
            *reinterpret_cast<float4*>(&Rpart[wv][lane][0]) = make_float4(rp[0], rp[1], rp[2], rp[3]);
            *reinterpret_cast<float4*>(&Rpart[wv][lane][4]) = make_float4(rp[4], rp[5], rp[6], rp[7]);
        }
        __syncthreads();
        if (t < NY * BS) {
            const int k = t >> 3, j = t & 7;
            float ssum = 0.f;
            #pragma unroll
            for (int w = 0; w < NWAVE; ++w) ssum += Rpart[w][k][j];
            Rr[k][j] = ssum;
        }
        __syncthreads();

        // ---- Phase D: per-scenario update + simplex projection (wave j) ----
        if (wv < BS) {
            const int j = wv, k = lane;
            const float r = Rr[k][j];
            const float gz = 2.0f * r - Yh[j][k];
            const float vz = Zs[j][k] - lr * gz;

            // bitonic sort (descending) across 64 lanes
            float sv = vz;
            #pragma unroll
            for (int sz = 2; sz <= 64; sz <<= 1) {
                #pragma unroll
                for (int st = sz >> 1; st > 0; st >>= 1) {
                    const float other = __shfl_xor(sv, st, 64);
                    const bool desc = ((lane & sz) == 0);
                    const bool lower = ((lane & st) == 0);
                    const float mx = fmaxf(sv, other), mn = fminf(sv, other);
                    sv = (lower == desc) ? mx : mn;
                }
            }
            // inclusive scan -> cumsum - 1
            float css = sv;
            #pragma unroll
            for (int off = 1; off < 64; off <<= 1) {
                const float nb = __shfl_up(css, off, 64);
                if (lane >= off) css += nb;
            }
            css -= 1.0f;
            const bool cond = (sv - css / (float)(lane + 1)) > 0.0f;
            const unsigned long long bal = __ballot(cond);
            const int idx = __popcll(bal) - 1;
            const float cssIdx = __shfl(css, idx, 64);
            const float theta = cssIdx / (float)(idx + 1);
            Zs[j][k] = fmaxf(vz - theta, 0.0f);
            if (lane == 0) {
                cS[j] = cS[j] - lr * gcS[j];
                lamS[j] = fmaxf(lamS[j] - lr * glamS[j], 0.0f);
            }
        }
        __syncthreads();
    }

    if (t < BS * NY) {
        const int j = t >> 6, k = t & 63;
        zout[(sc0 + j) * NY + k] = Zs[j][k];
    }
}

extern "C" void kernel_launch(void* const* d_in, const int* in_sizes, int n_in,
                              void* d_out, int out_size, void* d_ws, size_t ws_size,
                              hipStream_t stream) {
    const float* X   = (const float*)d_in[0];
    const float* Y   = (const float*)d_in[1];
    const float* rho = (const float*)d_in[2];
    const float* W   = (const float*)d_in[3];
    const float* b   = (const float*)d_in[4];

    float* out   = (float*)d_out;
    float* zout  = out;                 // Z_star: 2048*64
    float* yhat  = out + NOBS * NY;     // Y_hat:  2048*64
    float* ep    = (float*)d_ws;        // 2048*64 f32 = 512 KB
    float* epsum = ep + NOBS * NY;      // 1 f32

    hipMemsetAsync(epsum, 0, sizeof(float), stream);
    prep_kernel<<<NOBS / 4, 256, 0, stream>>>(X, Y, W, b, yhat, ep, epsum);
    solve_kernel<<<NOBS / BS, NT, 0, stream>>>(ep, yhat, epsum, rho, zout);
}